// Round 10
// baseline (904.685 us; speedup 1.0000x reference)
//
#include <hip/hip_runtime.h>

#define B_ 512
#define T_ 512
#define F_ 128
#define H_ 32
#define C_ 6
#define CH 32            // timesteps per chunk
#define NCH (T_ / CH)    // 16 chunks

// ---------------------------------------------------------------------------
// Fused LSTM, barrier-scheduled pipeline. 256 blocks x 384 threads (6 waves).
// Block b owns batch rows {2b, 2b+1}.
//   waves 0,1: scan consumers (row 2b / 2b+1)  [round-8 verified math]
//   waves 2,3: producers row 2b   (cols 0-63 / 64-127)
//   waves 4,5: producers row 2b+1
// Static schedule, one __syncthreads per phase, consumer one chunk behind:
//   phase ph: producers matvec chunk ph -> zring[ph&1], stage chunk ph+1 x
//             -> xst[(ph+1)&1]; consumers scan chunk ph-1 <- zring[(ph-1)&1].
// Slot parities never collide; the barrier stops any wave racing a full
// phase ahead. (Round 9's LDS-flag protocol raced; this is its auditable
// replacement.) mring is un-slotted (4 KB) -- no reuse, no parity race.
// Both role paths execute exactly NCH+1 barriers (wave-uniform branch).
// ---------------------------------------------------------------------------

__device__ __forceinline__ float sigmf(float xx) {
  return __builtin_amdgcn_rcpf(1.f + __expf(-xx));
}
__device__ __forceinline__ float tanhf_(float xx) {
  return __builtin_amdgcn_rcpf(1.f + __expf(-2.f * xx)) * 2.f - 1.f;
}

__global__ __launch_bounds__(384, 2) void k_fused(
    const float* __restrict__ x, const float* __restrict__ Wx,
    const float* __restrict__ bias, const float* __restrict__ Wh,
    const float* __restrict__ Wfc, const float* __restrict__ bfc,
    float* __restrict__ out)
{
  __shared__ float zring[2][2][CH][128];   // 64 KB [row][slot][t][col]
  __shared__ float xst  [2][2][CH][128];   // 64 KB [row][slot][t][f]
  __shared__ float mring[2][NCH][CH];      // 4 KB  [row][chunk][t]  (no reuse)

  const int tid  = threadIdx.x;
  const int wid  = tid >> 6;
  const int lane = tid & 63;
  const int brow = blockIdx.x * 2;

  if (wid >= 2) {
    // ------------------------------ producer ------------------------------
    const int p    = wid - 2;
    const int prow = p >> 1;
    const int hp   = p & 1;
    const int cb   = hp * 64;        // owned column range [cb, cb+64)
    const int sb   = hp * 16;        // staged timestep range [sb, sb+16)
    const int r    = brow + prow;

    float Wc[128];                   // Wx column (cb+lane), register-resident
#pragma unroll
    for (int f = 0; f < 128; ++f) Wc[f] = Wx[f * 128 + cb + lane];
    const float bb = bias[cb + lane];
    const float* xr = x + (size_t)r * (T_ * F_);

    // prologue: load + stage chunk 0 into xst[prow][0] and mring[prow][0]
    float2 xld[16];
#pragma unroll
    for (int s = 0; s < 16; ++s)
      xld[s] = *(const float2*)(xr + (sb + s) * F_ + 2 * lane);
#pragma unroll
    for (int s = 0; s < 16; ++s) {
      *(float2*)(&xst[prow][0][sb + s][2 * lane]) = xld[s];
      const bool nb = (xld[s].x != 0.f) || (xld[s].y != 0.f);
      const unsigned long long bal = __ballot(nb);
      if (lane == 0) mring[prow][0][sb + s] = bal ? 1.f : 0.f;
    }

    for (int ph = 0; ph <= NCH; ++ph) {
      __syncthreads();
      if (ph >= NCH) continue;       // last phase: consumers finish chunk 15
      const int slot = ph & 1;

      // issue next chunk's global loads early (latency hides under matvec)
      if (ph + 1 < NCH) {
#pragma unroll
        for (int s = 0; s < 16; ++s)
          xld[s] = *(const float2*)(xr + ((ph + 1) * CH + sb + s) * F_ + 2 * lane);
      }

      // matvec chunk ph: z[t][cb+lane] = bias + sum_f xst[t][f] * Wc[f]
      for (int t = 0; t < CH; ++t) {
        float z0 = bb, z1 = 0.f, z2 = 0.f, z3 = 0.f;
        const float* xp = &xst[prow][slot][t][0];
#pragma unroll
        for (int fq = 0; fq < 32; ++fq) {
          const float4 xf = *(const float4*)(xp + fq * 4);  // uniform broadcast
          z0 += xf.x * Wc[fq * 4 + 0];
          z1 += xf.y * Wc[fq * 4 + 1];
          z2 += xf.z * Wc[fq * 4 + 2];
          z3 += xf.w * Wc[fq * 4 + 3];
        }
        zring[prow][slot][t][cb + lane] = (z0 + z1) + (z2 + z3);
      }

      // stage chunk ph+1 into the other slot (read next phase, post-barrier)
      if (ph + 1 < NCH) {
#pragma unroll
        for (int s = 0; s < 16; ++s) {
          *(float2*)(&xst[prow][slot ^ 1][sb + s][2 * lane]) = xld[s];
          const bool nb = (xld[s].x != 0.f) || (xld[s].y != 0.f);
          const unsigned long long bal = __ballot(nb);
          if (lane == 0) mring[prow][ph + 1][sb + s] = bal ? 1.f : 0.f;
        }
      }
    }
    return;
  }

  // ------------------------------ consumer ------------------------------
  const int row  = wid;
  const int r    = brow + row;
  const int half = lane >> 5;
  const int j    = lane & 31;
  const int colA = half * 32 + j;        // i (half0) / f (half1)
  const int colB = 64 + half * 32 + j;   // g (half0) / o (half1)

  float WhA[32], WhB[32];
#pragma unroll
  for (int f = 0; f < 32; ++f) {
    WhA[f] = Wh[f * 128 + colA];
    WhB[f] = Wh[f * 128 + colB];
  }

  float hsc[32];                         // wave-uniform (SGPR via readlane)
#pragma unroll
  for (int f = 0; f < 32; ++f) hsc[f] = 0.f;
  float cj = 0.f, hj = 0.f;

  for (int ph = 0; ph <= NCH; ++ph) {
    __syncthreads();
    if (ph < 1) continue;                // phase 0: producers fill chunk 0
    const int c    = ph - 1;
    const int slot = c & 1;
    const float* zb = &zring[row][slot][0][0];
    const float* mb = &mring[row][c][0];

    // depth-4 register prefetch ring (statically indexed)
    float za[4], zc[4], mm[4];
#pragma unroll
    for (int u = 0; u < 4; ++u) {
      za[u] = zb[u * 128 + colA];
      zc[u] = zb[u * 128 + colB];
      mm[u] = mb[u];
    }
    for (int s0 = 0; s0 < 8; ++s0) {
#pragma unroll
      for (int u = 0; u < 4; ++u) {
        const int s = s0 * 4 + u;
        float zA0 = za[u], zA1 = 0.f;
        float zB0 = zc[u], zB1 = 0.f;
        const float m = mm[u];
        if (s0 < 7) {                    // refill slot u with step s+4
          za[u] = zb[(s + 4) * 128 + colA];
          zc[u] = zb[(s + 4) * 128 + colB];
          mm[u] = mb[s + 4];
        }
        // recurrent matvec: 64 v_fmac (sgpr*vgpr), 4 independent chains
#pragma unroll
        for (int f = 0; f < 16; ++f) {
          zA0 += hsc[2 * f]     * WhA[2 * f];
          zA1 += hsc[2 * f + 1] * WhA[2 * f + 1];
          zB0 += hsc[2 * f]     * WhB[2 * f];
          zB1 += hsc[2 * f + 1] * WhB[2 * f + 1];
        }
        const float zA = zA0 + zA1;           // half0: zi, half1: zf
        const float zB = zB0 + zB1;           // half0: zg, half1: zo
        const float oA = __shfl_xor(zA, 32);
        const float oB = __shfl_xor(zB, 32);
        const float zi = half ? oA : zA;
        const float zf = half ? zA : oA;
        const float zg = half ? oB : zB;
        const float zo = half ? zB : oB;

        const float ig = sigmf(zi);
        const float fg = sigmf(zf);
        const float gg = tanhf_(zg);
        const float og = sigmf(zo);
        const float cn = fg * cj + ig * gg;
        const float hn = og * tanhf_(cn);
        cj += m * (cn - cj);          // masked: keep previous state if m==0
        hj += m * (hn - hj);

        // broadcast h: 32 independent v_readlane -> uniform scalars
#pragma unroll
        for (int f = 0; f < 32; ++f)
          hsc[f] = __uint_as_float(__builtin_amdgcn_readlane(__float_as_uint(hj), f));
      }
    }
  }

  // FC + softmax (all lanes redundant from uniform h; lane 0 writes)
  float logits[C_];
#pragma unroll
  for (int c = 0; c < C_; ++c) {
    float aa = bfc[c];
#pragma unroll
    for (int f = 0; f < 32; ++f) aa += hsc[f] * Wfc[f * C_ + c];
    logits[c] = aa;
  }
  if (lane == 0) {
    float mx = logits[0];
#pragma unroll
    for (int c = 1; c < C_; ++c) mx = fmaxf(mx, logits[c]);
    float e[C_], sden = 0.f;
#pragma unroll
    for (int c = 0; c < C_; ++c) { e[c] = __expf(logits[c] - mx); sden += e[c]; }
    const float rs = 1.f / sden;
#pragma unroll
    for (int c = 0; c < C_; ++c) out[(size_t)r * C_ + c] = e[c] * rs;
  }
}

// ---------------------------------------------------------------------------
extern "C" void kernel_launch(void* const* d_in, const int* in_sizes, int n_in,
                              void* d_out, int out_size, void* d_ws, size_t ws_size,
                              hipStream_t stream) {
  const float* x   = (const float*)d_in[0];
  const float* Wx  = (const float*)d_in[1];
  const float* Wh  = (const float*)d_in[2];
  const float* bv  = (const float*)d_in[3];
  const float* Wfc = (const float*)d_in[4];
  const float* bfc = (const float*)d_in[5];
  float* out = (float*)d_out;

  k_fused<<<B_ / 2, 384, 0, stream>>>(x, Wx, bv, Wh, Wfc, bfc, out);
}